// Round 2
// baseline (789.573 us; speedup 1.0000x reference)
//
#include <hip/hip_runtime.h>

#define TL  2048
#define NB  4096
#define INSZ 8
#define HID 10

__device__ __forceinline__ float rcp_(float x) { return __builtin_amdgcn_rcpf(x); }

// Decomposition: 32 lanes per chain, 2 chains per wave, 2048 waves = 2 waves/SIMD.
// lane = (cg<<5) | (r2<<4) | j16.  Lane (j, r2) owns gate rows:
//   r2=0: row j (i-gate, sigmoid) and row 10+j (f-gate, sigmoid)
//   r2=1: row 20+j (g-gate, tanh)  and row 30+j (o-gate, sigmoid)
// 36 FMA/lane/step; gate exchange via 2x shfl_xor(16); both partners update
// c_j,h_j redundantly (stay in sync, no extra broadcast); h redistributed to
// the 16-lane group via 10 bpermutes. j16 in 10..15 are padding (mirror j=0).
__global__ void __launch_bounds__(64, 2) lstm_fused(
    const float* __restrict__ x,
    const float* __restrict__ h0,
    const float* __restrict__ c0,
    const float* __restrict__ Wih,
    const float* __restrict__ Whh,
    const float* __restrict__ bih,
    const float* __restrict__ bhh,
    const float* __restrict__ Wfc,
    const float* __restrict__ bfc,
    float* __restrict__ out)
{
    const int lane = threadIdx.x;
    const int j16  = lane & 15;
    const int r2   = (lane >> 4) & 1;
    const int cg   = lane >> 5;
    // bijective XCD swizzle: 2048 blocks % 8 == 0 -> each XCD gets a
    // contiguous 256-block (512-chain) range; the 4 chains sharing each
    // 128B x-line stay on one XCD.
    const int bid  = (int)blockIdx.x;
    const int swz  = (bid & 7) * ((int)gridDim.x >> 3) + (bid >> 3);
    const int n    = swz * 2 + cg;
    const int j    = (j16 < HID) ? j16 : 0;   // clamp padding lanes
    const int src  = lane & 48;               // own chain group + own r2 half

    const int row0 = r2 * 2 * HID + j;
    const int row1 = row0 + HID;

    // loop-invariant weights in VGPRs: 2 rows x (8+10) + 2 bias = 38 regs
    float w0i[INSZ], w1i[INSZ], w0h[HID], w1h[HID];
#pragma unroll
    for (int i = 0; i < INSZ; ++i) { w0i[i] = Wih[row0*INSZ+i]; w1i[i] = Wih[row1*INSZ+i]; }
#pragma unroll
    for (int k = 0; k < HID; ++k) { w0h[k] = Whh[row0*HID+k]; w1h[k] = Whh[row1*HID+k]; }
    const float bias0 = bih[row0] + bhh[row0];
    const float bias1 = bih[row1] + bhh[row1];

    // gate0 activation params: r2=0 -> sigmoid, r2=1 -> tanh = 2*sig(2x)-1
    const float kn0 = r2 ? -2.0f : -1.0f;
    const float m0  = r2 ?  2.0f :  1.0f;
    const float o0  = r2 ? -1.0f :  0.0f;

    float cst = c0[n * HID + j];
    float hst = h0[n * HID + j];

    const size_t xs = (size_t)NB * INSZ;
    const float* xp = x + (size_t)n * INSZ;

#define XLD(dst0, dst1, tt) do { \
        const float* p_ = xp + (size_t)(tt) * xs; \
        dst0 = *(const float4*)(p_); \
        dst1 = *(const float4*)(p_ + 4); \
    } while (0)

#define STEP(X0, X1) do { \
        float hv[HID]; \
        _Pragma("unroll") \
        for (int k = 0; k < HID; ++k) hv[k] = __shfl(hst, src + k, 64); \
        const float xv[INSZ] = {X0.x, X0.y, X0.z, X0.w, X1.x, X1.y, X1.z, X1.w}; \
        float a0e = bias0, a0o = 0.0f, a1e = bias1, a1o = 0.0f; \
        _Pragma("unroll") \
        for (int i = 0; i < INSZ; i += 2) { \
            a0e += w0i[i]   * xv[i];   a1e += w1i[i]   * xv[i]; \
            a0o += w0i[i+1] * xv[i+1]; a1o += w1i[i+1] * xv[i+1]; \
        } \
        _Pragma("unroll") \
        for (int k = 0; k < HID; k += 2) { \
            a0e += w0h[k]   * hv[k];   a1e += w1h[k]   * hv[k]; \
            a0o += w0h[k+1] * hv[k+1]; a1o += w1h[k+1] * hv[k+1]; \
        } \
        const float a0 = a0e + a0o; \
        const float a1 = a1e + a1o; \
        const float g0 = m0 * rcp_(1.0f + __expf(kn0 * a0)) + o0; \
        const float g1 = rcp_(1.0f + __expf(-a1)); \
        const float p0 = __shfl_xor(g0, 16, 64); \
        const float p1 = __shfl_xor(g1, 16, 64); \
        const float prod = g0 * p0;            /* i*g on both halves */ \
        const float fv = r2 ? p1 : g1; \
        const float ov = r2 ? g1 : p1; \
        cst = fv * cst + prod; \
        const float tc = 2.0f * rcp_(1.0f + __expf(-2.0f * cst)) - 1.0f; \
        hst = ov * tc; \
    } while (0)

    // 8-step unrolled ping-pong with register prefetch of x (4-7 steps ahead).
    float4 A0,A1,B0,B1,C0,C1,D0,D1, E0,E1,F0,F1,G0,G1,H0,H1;
    XLD(A0,A1,0); XLD(B0,B1,1); XLD(C0,C1,2); XLD(D0,D1,3);

    for (int t = 0; t < TL; t += 8) {
        XLD(E0,E1,t+4); XLD(F0,F1,t+5); XLD(G0,G1,t+6); XLD(H0,H1,t+7);
        STEP(A0,A1); STEP(B0,B1); STEP(C0,C1); STEP(D0,D1);
        const int t8 = t + 8;
        const int ta = (t8     < TL) ? t8     : 0;  // clamped dummy reload on last iter
        const int tb = (t8 + 1 < TL) ? t8 + 1 : 0;
        const int tc_ = (t8 + 2 < TL) ? t8 + 2 : 0;
        const int td = (t8 + 3 < TL) ? t8 + 3 : 0;
        XLD(A0,A1,ta); XLD(B0,B1,tb); XLD(C0,C1,tc_); XLD(D0,D1,td);
        STEP(E0,E1); STEP(F0,F1); STEP(G0,G1); STEP(H0,H1);
    }

#undef STEP
#undef XLD

    // epilogue: y = h @ W_fc.T + b_fc, then dump h and c
    float hv[HID];
#pragma unroll
    for (int k = 0; k < HID; ++k) hv[k] = __shfl(hst, src + k, 64);

    if (r2 == 0 && j16 < INSZ) {
        float acc = bfc[j16];
#pragma unroll
        for (int k = 0; k < HID; ++k) acc += Wfc[j16 * HID + k] * hv[k];
        out[n * INSZ + j16] = acc;
    }
    if (r2 == 0 && j16 < HID) {
        out[NB * INSZ + n * HID + j16] = hst;
    }
    if (r2 == 1 && j16 < HID) {
        out[NB * INSZ + NB * HID + n * HID + j16] = cst;
    }
}

extern "C" void kernel_launch(void* const* d_in, const int* in_sizes, int n_in,
                              void* d_out, int out_size, void* d_ws, size_t ws_size,
                              hipStream_t stream) {
    const float* x   = (const float*)d_in[0];
    const float* h0  = (const float*)d_in[1];
    const float* c0  = (const float*)d_in[2];
    const float* Wih = (const float*)d_in[3];
    const float* Whh = (const float*)d_in[4];
    const float* bih = (const float*)d_in[5];
    const float* bhh = (const float*)d_in[6];
    const float* Wfc = (const float*)d_in[7];
    const float* bfc = (const float*)d_in[8];
    float* out = (float*)d_out;

    lstm_fused<<<NB / 2, 64, 0, stream>>>(x, h0, c0, Wih, Whh, bih, bhh, Wfc, bfc, out);
}

// Round 3
// 520.712 us; speedup vs baseline: 1.5163x; 1.5163x over previous
//
#include <hip/hip_runtime.h>

#define TL  2048
#define NB  4096
#define INSZ 8
#define HID 10
#define LOG2E 1.4426950408889634f

__device__ __forceinline__ float rcp_(float x)  { return __builtin_amdgcn_rcpf(x); }
__device__ __forceinline__ float exp2_(float x) { return __builtin_amdgcn_exp2f(x); }

// row_ror:R within 16-lane DPP rows: dst[i] = src[(i-R)&15] (VALU pipe, no DS).
template<int R> __device__ __forceinline__ float rot16(float x) {
    if constexpr (R == 0) {
        return x;
    } else {
        return __int_as_float(__builtin_amdgcn_update_dpp(
            __float_as_int(x), __float_as_int(x), 0x120 + R, 0xF, 0xF, false));
    }
}

// h-dot: 15 independent DPP rotations of h + 64 FMA with pre-rotated weights.
// Even/odd accumulator split keeps the FMA dep chain <= 8 deep.
template<int R> __device__ __forceinline__ void hdot(float h, const float (&wr)[4][16],
        float& a0e, float& a0o, float& a1e, float& a1o,
        float& a2e, float& a2o, float& a3e, float& a3o) {
    if constexpr (R < 16) {
        const float v = rot16<R>(h);
        if constexpr (R & 1) {
            a0o += wr[0][R] * v; a1o += wr[1][R] * v;
            a2o += wr[2][R] * v; a3o += wr[3][R] * v;
        } else {
            a0e += wr[0][R] * v; a1e += wr[1][R] * v;
            a2e += wr[2][R] * v; a3e += wr[3][R] * v;
        }
        hdot<R + 1>(h, wr, a0e, a0o, a1e, a1o, a2e, a2o, a3e, a3o);
    }
}

__device__ __forceinline__ void lstm_step(const float4& X0, const float4& X1,
        const float (&wx)[4][INSZ], const float (&wr)[4][16], const float (&bs)[4],
        float& hst, float& cst) {
    const float xv[INSZ] = {X0.x, X0.y, X0.z, X0.w, X1.x, X1.y, X1.z, X1.w};
    float a0e = bs[0], a1e = bs[1], a2e = bs[2], a3e = bs[3];
    float a0o = 0.f,   a1o = 0.f,   a2o = 0.f,   a3o = 0.f;
#pragma unroll
    for (int i = 0; i < INSZ; i += 2) {
        a0e += wx[0][i] * xv[i];     a1e += wx[1][i] * xv[i];
        a2e += wx[2][i] * xv[i];     a3e += wx[3][i] * xv[i];
        a0o += wx[0][i+1] * xv[i+1]; a1o += wx[1][i+1] * xv[i+1];
        a2o += wx[2][i+1] * xv[i+1]; a3o += wx[3][i+1] * xv[i+1];
    }
    hdot<0>(hst, wr, a0e, a0o, a1e, a1o, a2e, a2o, a3e, a3o);
    // weights pre-scaled by -log2e (i,f,o) / -2*log2e (g): activations are pure exp2 forms.
    const float a0 = a0e + a0o, a1 = a1e + a1o, a2 = a2e + a2o, a3 = a3e + a3o;
    const float ig = rcp_(1.f + exp2_(a0));
    const float fg = rcp_(1.f + exp2_(a1));
    const float gg = 2.f * rcp_(1.f + exp2_(a2)) - 1.f;
    const float og = rcp_(1.f + exp2_(a3));
    cst = fg * cst + ig * gg;
    const float th = 2.f * rcp_(1.f + exp2_(cst * (-2.f * LOG2E))) - 1.f;
    hst = og * th;
}

// 16 lanes per chain, 4 chains per wave, 1024 waves = 1 wave/SIMD.
// Lane j16 (j16<10) owns hidden unit j: gate rows {j,10+j,20+j,30+j}.
// h exchanged via DPP row_ror (no DS on the recurrence path).
// Padding lanes j16 in 10..15 run unit 0 on bounded garbage (|h|<1 always);
// their values are killed by zero weights in every real lane's dot product.
__global__ void __attribute__((amdgpu_flat_work_group_size(64, 64)))
                __attribute__((amdgpu_waves_per_eu(1)))
lstm_fused(
    const float* __restrict__ x,
    const float* __restrict__ h0,
    const float* __restrict__ c0,
    const float* __restrict__ Wih,
    const float* __restrict__ Whh,
    const float* __restrict__ bih,
    const float* __restrict__ bhh,
    const float* __restrict__ Wfc,
    const float* __restrict__ bfc,
    float* __restrict__ out)
{
    const int lane = threadIdx.x;
    const int j16  = lane & 15;
    const int grp  = lane >> 4;
    const int n    = ((int)blockIdx.x << 2) + grp;
    const int j    = (j16 < HID) ? j16 : 0;   // clamp padding lanes
    const int src  = lane & 48;               // 16-lane group base

    // Weights in VGPRs, activation scale folded in: s = -log2e (i,f,o), -2log2e (g).
    float wx[4][INSZ], wr[4][16], bs[4];
#pragma unroll
    for (int g = 0; g < 4; ++g) {
        const int row = g * HID + j;
        const float s = (g == 2 ? -2.0f : -1.0f) * LOG2E;
#pragma unroll
        for (int i = 0; i < INSZ; ++i) wx[g][i] = Wih[row * INSZ + i] * s;
        bs[g] = (bih[row] + bhh[row]) * s;
#pragma unroll
        for (int r = 0; r < 16; ++r) {
            const int k = (j16 - r) & 15;     // lane holding the value after ror:r
            wr[g][r] = (k < HID) ? Whh[row * HID + k] * s : 0.0f;
        }
    }

    float cst = c0[n * HID + j];
    float hst = h0[n * HID + j];

    const size_t xs = (size_t)NB * INSZ;
    const float* xp = x + (size_t)n * INSZ;

#define XLD(dst0, dst1, tt) do { \
        const float* p_ = xp + (size_t)(tt) * xs; \
        dst0 = *(const float4*)(p_); \
        dst1 = *(const float4*)(p_ + 4); \
    } while (0)

    // 8-step unrolled ping-pong register prefetch (4-7 steps ahead ~ >1100cy).
    float4 A0,A1,B0,B1,C0,C1,D0,D1, E0,E1,F0,F1,G0,G1,H0,H1;
    XLD(A0,A1,0); XLD(B0,B1,1); XLD(C0,C1,2); XLD(D0,D1,3);

    for (int t = 0; t < TL; t += 8) {
        XLD(E0,E1,t+4); XLD(F0,F1,t+5); XLD(G0,G1,t+6); XLD(H0,H1,t+7);
        lstm_step(A0,A1, wx,wr,bs, hst,cst);
        lstm_step(B0,B1, wx,wr,bs, hst,cst);
        lstm_step(C0,C1, wx,wr,bs, hst,cst);
        lstm_step(D0,D1, wx,wr,bs, hst,cst);
        const int t8 = t + 8;
        const int ta = (t8     < TL) ? t8     : 0;  // clamped dummy reload on last iter
        const int tb = (t8 + 1 < TL) ? t8 + 1 : 0;
        const int tc = (t8 + 2 < TL) ? t8 + 2 : 0;
        const int td = (t8 + 3 < TL) ? t8 + 3 : 0;
        XLD(A0,A1,ta); XLD(B0,B1,tb); XLD(C0,C1,tc); XLD(D0,D1,td);
        lstm_step(E0,E1, wx,wr,bs, hst,cst);
        lstm_step(F0,F1, wx,wr,bs, hst,cst);
        lstm_step(G0,G1, wx,wr,bs, hst,cst);
        lstm_step(H0,H1, wx,wr,bs, hst,cst);
    }
#undef XLD

    // epilogue (one-time, DS shuffles fine here): y = h @ W_fc.T + b_fc; dump h, c
    float hv[HID];
#pragma unroll
    for (int k = 0; k < HID; ++k) hv[k] = __shfl(hst, src + k, 64);

    if (j16 < INSZ) {
        float acc = bfc[j16];
#pragma unroll
        for (int k = 0; k < HID; ++k) acc += Wfc[j16 * HID + k] * hv[k];
        out[n * INSZ + j16] = acc;
    }
    if (j16 < HID) {
        out[NB * INSZ + n * HID + j16] = hst;
        out[NB * INSZ + NB * HID + n * HID + j16] = cst;
    }
}

extern "C" void kernel_launch(void* const* d_in, const int* in_sizes, int n_in,
                              void* d_out, int out_size, void* d_ws, size_t ws_size,
                              hipStream_t stream) {
    const float* x   = (const float*)d_in[0];
    const float* h0  = (const float*)d_in[1];
    const float* c0  = (const float*)d_in[2];
    const float* Wih = (const float*)d_in[3];
    const float* Whh = (const float*)d_in[4];
    const float* bih = (const float*)d_in[5];
    const float* bhh = (const float*)d_in[6];
    const float* Wfc = (const float*)d_in[7];
    const float* bfc = (const float*)d_in[8];
    float* out = (float*)d_out;

    lstm_fused<<<NB / 4, 64, 0, stream>>>(x, h0, c0, Wih, Whh, bih, bhh, Wfc, bfc, out);
}

// Round 4
// 500.796 us; speedup vs baseline: 1.5766x; 1.0398x over previous
//
#include <hip/hip_runtime.h>

#define TL  2048
#define NB  4096
#define INSZ 8
#define HID 10
#define LOG2E 1.4426950408889634f

typedef float v2f __attribute__((ext_vector_type(2)));

__device__ __forceinline__ float rcp_(float x)  { return __builtin_amdgcn_rcpf(x); }
__device__ __forceinline__ float exp2_(float x) { return __builtin_amdgcn_exp2f(x); }

// row_newbcast:K (DPP ctrl 0x150+K, gfx90a+): every lane in each 16-lane row
// receives src from lane K of that row. VALU pipe, no DS.
template<int K> __device__ __forceinline__ float bcast16(float x) {
    return __int_as_float(__builtin_amdgcn_update_dpp(
        0, __float_as_int(x), 0x150 + K, 0xF, 0xF, false));
}

// v_pk_fma_f32: acc.lo += w.lo * sel(x); acc.hi += w.hi * sel(x)
// LL: both halves use x.lo (op_sel_hi[1]=0). HH: both halves use x.hi.
#define PK_FMA_LL(acc, w, x) asm("v_pk_fma_f32 %0, %1, %2, %0 op_sel_hi:[1,0,1]" \
                                 : "+v"(acc) : "v"(w), "v"(x))
#define PK_FMA_HH(acc, w, x) asm("v_pk_fma_f32 %0, %1, %2, %0 op_sel:[0,1,0] op_sel_hi:[1,1,1]" \
                                 : "+v"(acc) : "v"(w), "v"(x))
#define PK_ADD(d, a, b)      asm("v_pk_add_f32 %0, %1, %2" : "=v"(d) : "v"(a), "v"(b))

struct LWeights {
    v2f wx01[INSZ], wx23[INSZ];   // (i,f) and (g,o) gate pairs, scale folded
    v2f wh01[HID],  wh23[HID];
    v2f b01, b23;
};

__device__ __forceinline__ void lstm_step(const float4& X0, const float4& X1,
        const LWeights& W, float& hst, float& cst) {
    v2f a01e = W.b01, a23e = W.b23;
    v2f a01o = {0.f, 0.f}, a23o = {0.f, 0.f};
    const v2f xp0 = {X0.x, X0.y}, xp1 = {X0.z, X0.w};
    const v2f xp2 = {X1.x, X1.y}, xp3 = {X1.z, X1.w};
    // x-dot: 16 pk_fma, even i -> e-bank (LL), odd i -> o-bank (HH)
    PK_FMA_LL(a01e, W.wx01[0], xp0); PK_FMA_LL(a23e, W.wx23[0], xp0);
    PK_FMA_HH(a01o, W.wx01[1], xp0); PK_FMA_HH(a23o, W.wx23[1], xp0);
    PK_FMA_LL(a01e, W.wx01[2], xp1); PK_FMA_LL(a23e, W.wx23[2], xp1);
    PK_FMA_HH(a01o, W.wx01[3], xp1); PK_FMA_HH(a23o, W.wx23[3], xp1);
    PK_FMA_LL(a01e, W.wx01[4], xp2); PK_FMA_LL(a23e, W.wx23[4], xp2);
    PK_FMA_HH(a01o, W.wx01[5], xp2); PK_FMA_HH(a23o, W.wx23[5], xp2);
    PK_FMA_LL(a01e, W.wx01[6], xp3); PK_FMA_LL(a23e, W.wx23[6], xp3);
    PK_FMA_HH(a01o, W.wx01[7], xp3); PK_FMA_HH(a23o, W.wx23[7], xp3);
    // h-dot: 10 bcast + 20 pk_fma (hd.y is never read: LL selects lo)
    v2f hd = {0.f, 0.f};
#define HTERM(K, A01, A23) \
    hd.x = bcast16<K>(hst); \
    PK_FMA_LL(A01, W.wh01[K], hd); PK_FMA_LL(A23, W.wh23[K], hd)
    HTERM(0, a01e, a23e); HTERM(1, a01o, a23o);
    HTERM(2, a01e, a23e); HTERM(3, a01o, a23o);
    HTERM(4, a01e, a23e); HTERM(5, a01o, a23o);
    HTERM(6, a01e, a23e); HTERM(7, a01o, a23o);
    HTERM(8, a01e, a23e); HTERM(9, a01o, a23o);
#undef HTERM
    v2f a01, a23;
    PK_ADD(a01, a01e, a01o);
    PK_ADD(a23, a23e, a23o);
    // weights pre-scaled by -log2e (i,f,o) / -2log2e (g): pure exp2 activations
    const float ig = rcp_(1.f + exp2_(a01.x));
    const float fg = rcp_(1.f + exp2_(a01.y));
    const float gg = 2.f * rcp_(1.f + exp2_(a23.x)) - 1.f;
    const float og = rcp_(1.f + exp2_(a23.y));
    cst = fg * cst + ig * gg;
    const float th = 2.f * rcp_(1.f + exp2_(cst * (-2.f * LOG2E))) - 1.f;
    hst = og * th;
}

// 16 lanes per chain, 4 chains per wave, 1024 waves = 1 wave/SIMD.
// Lane j16<10 owns hidden unit j: gate rows {j,10+j,20+j,30+j}.
// h exchanged via DPP row_newbcast (VALU pipe; reads only lanes 0..9, so
// padding lanes' garbage never propagates).
__global__ void __attribute__((amdgpu_flat_work_group_size(64, 64)))
                __attribute__((amdgpu_waves_per_eu(1)))
lstm_fused(
    const float* __restrict__ x,
    const float* __restrict__ h0,
    const float* __restrict__ c0,
    const float* __restrict__ Wih,
    const float* __restrict__ Whh,
    const float* __restrict__ bih,
    const float* __restrict__ bhh,
    const float* __restrict__ Wfc,
    const float* __restrict__ bfc,
    float* __restrict__ out)
{
    const int lane = threadIdx.x;
    const int j16  = lane & 15;
    const int grp  = lane >> 4;
    const int n    = ((int)blockIdx.x << 2) + grp;
    const int j    = (j16 < HID) ? j16 : 0;   // clamp padding lanes
    const int src  = lane & 48;               // 16-lane group base

    const int ri = j, rf = HID + j, rg = 2 * HID + j, ro = 3 * HID + j;
    const float si = -LOG2E, sg = -2.f * LOG2E;

    LWeights W;
#pragma unroll
    for (int i = 0; i < INSZ; ++i) {
        W.wx01[i] = (v2f){Wih[ri * INSZ + i] * si, Wih[rf * INSZ + i] * si};
        W.wx23[i] = (v2f){Wih[rg * INSZ + i] * sg, Wih[ro * INSZ + i] * si};
    }
#pragma unroll
    for (int k = 0; k < HID; ++k) {
        W.wh01[k] = (v2f){Whh[ri * HID + k] * si, Whh[rf * HID + k] * si};
        W.wh23[k] = (v2f){Whh[rg * HID + k] * sg, Whh[ro * HID + k] * si};
    }
    W.b01 = (v2f){(bih[ri] + bhh[ri]) * si, (bih[rf] + bhh[rf]) * si};
    W.b23 = (v2f){(bih[rg] + bhh[rg]) * sg, (bih[ro] + bhh[ro]) * si};

    float cst = c0[n * HID + j];
    float hst = h0[n * HID + j];

    const size_t xs = (size_t)NB * INSZ;
    const float* xp = x + (size_t)n * INSZ;

#define XLD(dst0, dst1, tt) do { \
        const float* p_ = xp + (size_t)(tt) * xs; \
        dst0 = *(const float4*)(p_); \
        dst1 = *(const float4*)(p_ + 4); \
    } while (0)

    // 8-step unrolled ping-pong register prefetch (4-7 steps ahead).
    float4 A0,A1,B0,B1,C0,C1,D0,D1, E0,E1,F0,F1,G0,G1,H0,H1;
    XLD(A0,A1,0); XLD(B0,B1,1); XLD(C0,C1,2); XLD(D0,D1,3);

    for (int t = 0; t < TL; t += 8) {
        XLD(E0,E1,t+4); XLD(F0,F1,t+5); XLD(G0,G1,t+6); XLD(H0,H1,t+7);
        lstm_step(A0,A1, W, hst,cst);
        lstm_step(B0,B1, W, hst,cst);
        lstm_step(C0,C1, W, hst,cst);
        lstm_step(D0,D1, W, hst,cst);
        const int t8 = t + 8;
        const int ta = (t8     < TL) ? t8     : 0;  // clamped dummy reload on last iter
        const int tb = (t8 + 1 < TL) ? t8 + 1 : 0;
        const int tc = (t8 + 2 < TL) ? t8 + 2 : 0;
        const int td = (t8 + 3 < TL) ? t8 + 3 : 0;
        XLD(A0,A1,ta); XLD(B0,B1,tb); XLD(C0,C1,tc); XLD(D0,D1,td);
        lstm_step(E0,E1, W, hst,cst);
        lstm_step(F0,F1, W, hst,cst);
        lstm_step(G0,G1, W, hst,cst);
        lstm_step(H0,H1, W, hst,cst);
    }
#undef XLD

    // epilogue (one-time, DS shuffles fine here): y = h @ W_fc.T + b_fc; dump h, c
    float hv[HID];
#pragma unroll
    for (int k = 0; k < HID; ++k) hv[k] = __shfl(hst, src + k, 64);

    if (j16 < INSZ) {
        float acc = bfc[j16];
#pragma unroll
        for (int k = 0; k < HID; ++k) acc += Wfc[j16 * HID + k] * hv[k];
        out[n * INSZ + j16] = acc;
    }
    if (j16 < HID) {
        out[NB * INSZ + n * HID + j16] = hst;
        out[NB * INSZ + NB * HID + n * HID + j16] = cst;
    }
}

extern "C" void kernel_launch(void* const* d_in, const int* in_sizes, int n_in,
                              void* d_out, int out_size, void* d_ws, size_t ws_size,
                              hipStream_t stream) {
    const float* x   = (const float*)d_in[0];
    const float* h0  = (const float*)d_in[1];
    const float* c0  = (const float*)d_in[2];
    const float* Wih = (const float*)d_in[3];
    const float* Whh = (const float*)d_in[4];
    const float* bih = (const float*)d_in[5];
    const float* bhh = (const float*)d_in[6];
    const float* Wfc = (const float*)d_in[7];
    const float* bfc = (const float*)d_in[8];
    float* out = (float*)d_out;

    lstm_fused<<<NB / 4, 64, 0, stream>>>(x, h0, c0, Wih, Whh, bih, bhh, Wfc, bfc, out);
}

// Round 7
// 485.591 us; speedup vs baseline: 1.6260x; 1.0313x over previous
//
#include <hip/hip_runtime.h>
#include <stdint.h>

#define TL  2048
#define NB  4096
#define INSZ 8
#define HID 10
#define LOG2E 1.4426950408889634f
#define XS (NB * INSZ)            // floats per timestep slab
#define TSTEPS 8                  // timesteps per staged tile (1 KB)
#define NBUF 4
#define NTILES (TL / TSTEPS)      // 256

typedef float v2f __attribute__((ext_vector_type(2)));

__device__ __forceinline__ float rcp_(float x)  { return __builtin_amdgcn_rcpf(x); }
__device__ __forceinline__ float exp2_(float x) { return __builtin_amdgcn_exp2f(x); }

// row_newbcast:K (DPP ctrl 0x150+K): every lane of each 16-lane row receives
// src from lane K of that row. VALU pipe, no DS.
template<int K> __device__ __forceinline__ float bcast16(float x) {
    return __int_as_float(__builtin_amdgcn_update_dpp(
        __float_as_int(x), __float_as_int(x), 0x150 + K, 0xF, 0xF, false));
}

// v_pk_fma_f32: acc.lo += w.lo * sel(x); acc.hi += w.hi * sel(x)
#define PK_FMA_LL(acc, w, x) asm("v_pk_fma_f32 %0, %1, %2, %0 op_sel_hi:[1,0,1]" \
                                 : "+v"(acc) : "v"(w), "v"(x))
#define PK_FMA_HH(acc, w, x) asm("v_pk_fma_f32 %0, %1, %2, %0 op_sel:[0,1,0] op_sel_hi:[1,1,1]" \
                                 : "+v"(acc) : "v"(w), "v"(x))
#define PK_ADD(d, a, b)      asm("v_pk_add_f32 %0, %1, %2" : "=v"(d) : "v"(a), "v"(b))

struct LWeights {
    v2f wx01[INSZ], wx23[INSZ];   // (i,f) and (g,o) gate pairs, scale folded
    v2f wh01[HID],  wh23[HID];
    v2f b01, b23;
};

__device__ __forceinline__ void lstm_step(const float4& X0, const float4& X1,
        const LWeights& W, float& hst, float& cst) {
    v2f a01e = W.b01, a23e = W.b23;
    v2f a01o = {0.f, 0.f}, a23o = {0.f, 0.f};
    const v2f xp0 = {X0.x, X0.y}, xp1 = {X0.z, X0.w};
    const v2f xp2 = {X1.x, X1.y}, xp3 = {X1.z, X1.w};
    PK_FMA_LL(a01e, W.wx01[0], xp0); PK_FMA_LL(a23e, W.wx23[0], xp0);
    PK_FMA_HH(a01o, W.wx01[1], xp0); PK_FMA_HH(a23o, W.wx23[1], xp0);
    PK_FMA_LL(a01e, W.wx01[2], xp1); PK_FMA_LL(a23e, W.wx23[2], xp1);
    PK_FMA_HH(a01o, W.wx01[3], xp1); PK_FMA_HH(a23o, W.wx23[3], xp1);
    PK_FMA_LL(a01e, W.wx01[4], xp2); PK_FMA_LL(a23e, W.wx23[4], xp2);
    PK_FMA_HH(a01o, W.wx01[5], xp2); PK_FMA_HH(a23o, W.wx23[5], xp2);
    PK_FMA_LL(a01e, W.wx01[6], xp3); PK_FMA_LL(a23e, W.wx23[6], xp3);
    PK_FMA_HH(a01o, W.wx01[7], xp3); PK_FMA_HH(a23o, W.wx23[7], xp3);
    v2f hd = {0.f, 0.f};
#define HTERM(K, A01, A23) \
    hd.x = bcast16<K>(hst); \
    PK_FMA_LL(A01, W.wh01[K], hd); PK_FMA_LL(A23, W.wh23[K], hd)
    HTERM(0, a01e, a23e); HTERM(1, a01o, a23o);
    HTERM(2, a01e, a23e); HTERM(3, a01o, a23o);
    HTERM(4, a01e, a23e); HTERM(5, a01o, a23o);
    HTERM(6, a01e, a23e); HTERM(7, a01o, a23o);
    HTERM(8, a01e, a23e); HTERM(9, a01o, a23o);
#undef HTERM
    v2f a01, a23;
    PK_ADD(a01, a01e, a01o);
    PK_ADD(a23, a23e, a23o);
    // weights pre-scaled by -log2e (i,f,o) / -2log2e (g): pure exp2 activations
    const float ig = rcp_(1.f + exp2_(a01.x));
    const float fg = rcp_(1.f + exp2_(a01.y));
    const float gg = 2.f * rcp_(1.f + exp2_(a23.x)) - 1.f;
    const float og = rcp_(1.f + exp2_(a23.y));
    cst = fg * cst + ig * gg;
    const float th = 2.f * rcp_(1.f + exp2_(cst * (-2.f * LOG2E))) - 1.f;
    hst = og * th;
}

// One global_load_lds dwordx4: lane l's 16 B -> ldsbase + l*16 (wave-uniform
// base, linear lane layout — m104 rule). Data dependency of consumers is
// through LDS (memory), so "memory"-clobbered waits order them correctly —
// no regalloc-copy hazard (the R6 failure mode).
__device__ __forceinline__ void stage_tile(const float* gsrc_lane, float* ldsbase) {
    __builtin_amdgcn_global_load_lds(
        (const __attribute__((address_space(1))) void*)(uintptr_t)gsrc_lane,
        (__attribute__((address_space(3))) void*)(uint32_t)(uintptr_t)ldsbase,
        16, 0, 0);
}

// Consume one 8-step tile from LDS after a counted vmcnt wait.
template<int VM>
__device__ __forceinline__ void consume_tile(const float (&xb)[TSTEPS][4][INSZ],
        int grp, const LWeights& W, float& hst, float& cst) {
    __builtin_amdgcn_sched_barrier(0);
    asm volatile("s_waitcnt vmcnt(%0)" :: "i"(VM) : "memory");
    __builtin_amdgcn_sched_barrier(0);
#pragma unroll
    for (int s = 0; s < TSTEPS; ++s) {
        const float4 xlo = *(const float4*)&xb[s][grp][0];
        const float4 xhi = *(const float4*)&xb[s][grp][4];
        lstm_step(xlo, xhi, W, hst, cst);
    }
}

// 16 lanes per chain, 4 chains per wave, 1024 waves = 1 wave/SIMD.
// Lane j16<10 owns hidden unit j: gate rows {j,10+j,20+j,30+j}.
// h exchanged via DPP row_newbcast. x staged via 4-deep LDS pipeline.
__global__ void __attribute__((amdgpu_flat_work_group_size(64, 64)))
                __attribute__((amdgpu_waves_per_eu(1)))
lstm_fused(
    const float* __restrict__ x,
    const float* __restrict__ h0,
    const float* __restrict__ c0,
    const float* __restrict__ Wih,
    const float* __restrict__ Whh,
    const float* __restrict__ bih,
    const float* __restrict__ bhh,
    const float* __restrict__ Wfc,
    const float* __restrict__ bfc,
    float* __restrict__ out)
{
    __shared__ float xbuf[NBUF][TSTEPS][4][INSZ];   // 4 KB

    const int lane = threadIdx.x;
    const int j16  = lane & 15;
    const int grp  = lane >> 4;
    const int n    = ((int)blockIdx.x << 2) + grp;
    const int j    = (j16 < HID) ? j16 : 0;   // clamp padding lanes
    const int src  = lane & 48;               // 16-lane group base

    const int ri = j, rf = HID + j, rg = 2 * HID + j, ro = 3 * HID + j;
    const float si = -LOG2E, sg = -2.f * LOG2E;

    LWeights W;
#pragma unroll
    for (int i = 0; i < INSZ; ++i) {
        W.wx01[i] = (v2f){Wih[ri * INSZ + i] * si, Wih[rf * INSZ + i] * si};
        W.wx23[i] = (v2f){Wih[rg * INSZ + i] * sg, Wih[ro * INSZ + i] * si};
    }
#pragma unroll
    for (int k = 0; k < HID; ++k) {
        W.wh01[k] = (v2f){Whh[ri * HID + k] * si, Whh[rf * HID + k] * si};
        W.wh23[k] = (v2f){Whh[rg * HID + k] * sg, Whh[ro * HID + k] * si};
    }
    W.b01 = (v2f){(bih[ri] + bhh[ri]) * si, (bih[rf] + bhh[rf]) * si};
    W.b23 = (v2f){(bih[rg] + bhh[rg]) * sg, (bih[ro] + bhh[ro]) * si};

    float cst = c0[n * HID + j];
    float hst = h0[n * HID + j];

    // Per-lane staging source: lane l covers (ts = l>>3, chain = (l>>1)&3,
    // half = l&1) -> LDS byte l*16 matches xbuf[..][ts][chain][half*4..+3].
    const int ts = lane >> 3, ch = (lane >> 1) & 3, hf = lane & 1;
    const float* gl = x + (size_t)ts * XS
                        + (size_t)((((int)blockIdx.x << 2) + ch) * INSZ + hf * 4);

    // Prologue: stage tiles 0..3. Compiler-fences keep intrinsic issue order
    // (vmcnt retirement mapping depends on it).
    asm volatile("" ::: "memory");
#pragma unroll
    for (int b = 0; b < NBUF; ++b) {
        stage_tile(gl, &xbuf[b][0][0][0]);
        asm volatile("" ::: "memory");
        gl += (size_t)TSTEPS * XS;
    }

    // Main: 252 tiles with reissue; counted vmcnt(3) completes exactly the
    // oldest (this tile's) staging load. lgkmcnt(0) guarantees the ds_reads
    // of the buffer retired before its DMA rewrite is issued.
    for (int tile = 0; tile < NTILES - NBUF; ++tile) {
        const int b = tile & (NBUF - 1);
        consume_tile<3>(xbuf[b], grp, W, hst, cst);
        asm volatile("s_waitcnt lgkmcnt(0)" ::: "memory");
        stage_tile(gl, &xbuf[b][0][0][0]);
        asm volatile("" ::: "memory");
        gl += (size_t)TSTEPS * XS;
    }
    // Drain: tiles 252..255, descending counted waits, no reissue.
    consume_tile<3>(xbuf[0], grp, W, hst, cst);
    consume_tile<2>(xbuf[1], grp, W, hst, cst);
    consume_tile<1>(xbuf[2], grp, W, hst, cst);
    consume_tile<0>(xbuf[3], grp, W, hst, cst);

    // epilogue (one-time, DS shuffles fine here): y = h @ W_fc.T + b_fc; dump h, c
    float hv[HID];
#pragma unroll
    for (int k = 0; k < HID; ++k) hv[k] = __shfl(hst, src + k, 64);

    if (j16 < INSZ) {
        float acc = bfc[j16];
#pragma unroll
        for (int k = 0; k < HID; ++k) acc += Wfc[j16 * HID + k] * hv[k];
        out[n * INSZ + j16] = acc;
    }
    if (j16 < HID) {
        out[NB * INSZ + n * HID + j16] = hst;
        out[NB * INSZ + NB * HID + n * HID + j16] = cst;
    }
}

extern "C" void kernel_launch(void* const* d_in, const int* in_sizes, int n_in,
                              void* d_out, int out_size, void* d_ws, size_t ws_size,
                              hipStream_t stream) {
    const float* x   = (const float*)d_in[0];
    const float* h0  = (const float*)d_in[1];
    const float* c0  = (const float*)d_in[2];
    const float* Wih = (const float*)d_in[3];
    const float* Whh = (const float*)d_in[4];
    const float* bih = (const float*)d_in[5];
    const float* bhh = (const float*)d_in[6];
    const float* Wfc = (const float*)d_in[7];
    const float* bfc = (const float*)d_in[8];
    float* out = (float*)d_out;

    lstm_fused<<<NB / 4, 64, 0, stream>>>(x, h0, c0, Wih, Whh, bih, bhh, Wfc, bfc, out);
}